// Round 13
// baseline (114.166 us; speedup 1.0000x reference)
//
#include <hip/hip_runtime.h>

typedef unsigned short ushort_t;
typedef __attribute__((ext_vector_type(4))) short short4_t;
typedef __attribute__((ext_vector_type(8))) short short8;
typedef __attribute__((ext_vector_type(4))) float floatx4;
typedef __attribute__((ext_vector_type(8))) __bf16 bf16x8;

__device__ __forceinline__ ushort_t f2b(float f) {
  union { float f; unsigned int i; } t; t.f = f;
  unsigned int u = t.i;
  return (ushort_t)((u + 0x7fffu + ((u >> 16) & 1u)) >> 16);  // RNE
}

__device__ __forceinline__ floatx4 mfma16(short8 a, short8 b, floatx4 c) {
  return __builtin_amdgcn_mfma_f32_16x16x32_bf16(
      __builtin_bit_cast(bf16x8, a), __builtin_bit_cast(bf16x8, b), c, 0, 0, 0);
}

__device__ __forceinline__ void gload16(const void* g, void* l) {
  __builtin_amdgcn_global_load_lds(
      (const __attribute__((address_space(1))) void*)g,
      (__attribute__((address_space(3))) void*)l, 16, 0, 0);
}

// ---------------------------------------------------------------------------
// D1: f2b of x/W_in/W_out (blocks 0..3071) + softmax+rel rows (blocks
// 3072..7167, 4 rows/block). VERIFIED round 10, unchanged.
// ---------------------------------------------------------------------------
__global__ __launch_bounds__(256) void k_sm_f2b(
    const float* __restrict__ S, const float* __restrict__ relv,
    ushort_t* __restrict__ P, float* __restrict__ R,
    const float* __restrict__ x, const float* __restrict__ Wi,
    const float* __restrict__ Wo, ushort_t* __restrict__ xb,
    ushort_t* __restrict__ Wib, ushort_t* __restrict__ Wob)
{
  __shared__ float mid[4][16];

  if (blockIdx.x < 3072) {
    const float* in; ushort_t* out; int i;
    if (blockIdx.x < 2048)      { in = x;  out = xb;  i = (blockIdx.x * 256 + threadIdx.x) * 8; }
    else if (blockIdx.x < 2560) { in = Wi; out = Wib; i = ((blockIdx.x - 2048) * 256 + threadIdx.x) * 8; }
    else                        { in = Wo; out = Wob; i = ((blockIdx.x - 2560) * 256 + threadIdx.x) * 8; }
    float4 a = *reinterpret_cast<const float4*>(in + i);
    float4 b = *reinterpret_cast<const float4*>(in + i + 4);
    short8 o;
    o[0] = (short)f2b(a.x); o[1] = (short)f2b(a.y);
    o[2] = (short)f2b(a.z); o[3] = (short)f2b(a.w);
    o[4] = (short)f2b(b.x); o[5] = (short)f2b(b.y);
    o[6] = (short)f2b(b.z); o[7] = (short)f2b(b.w);
    *reinterpret_cast<short8*>(out + i) = o;
    return;
  }

  const int wave = threadIdx.x >> 6, lane = threadIdx.x & 63;
  const int row = (blockIdx.x - 3072) * 4 + wave;   // h*1024 + s
  const int s = row & 1023;
  const float* src = S + (size_t)row * 1024;

  float v[4][4];
#pragma unroll
  for (int c = 0; c < 4; ++c) {
    float4 raw = *reinterpret_cast<const float4*>(src + c * 256 + lane * 4);
    v[c][0] = raw.x; v[c][1] = raw.y; v[c][2] = raw.z; v[c][3] = raw.w;
  }
  float m = -1e30f;
#pragma unroll
  for (int c = 0; c < 4; ++c)
#pragma unroll
    for (int e = 0; e < 4; ++e) m = fmaxf(m, v[c][e]);
#pragma unroll
  for (int d = 32; d; d >>= 1) m = fmaxf(m, __shfl_xor(m, d));

  float p[4][4];
  float tot = 0.f, sA = 0.f, sB = 0.f;
#pragma unroll
  for (int c = 0; c < 4; ++c) {
#pragma unroll
    for (int e = 0; e < 4; ++e) {
      int j = c * 256 + lane * 4 + e;
      float pe = __expf(v[c][e] - m);
      p[c][e] = pe;
      tot += pe;
      sA += (j <= s - 8) ? pe : 0.f;
      sB += (j >= s + 8) ? pe : 0.f;
    }
  }
#pragma unroll
  for (int d = 32; d; d >>= 1) {
    tot += __shfl_xor(tot, d);
    sA  += __shfl_xor(sA, d);
    sB  += __shfl_xor(sB, d);
  }
  const float inv = 1.0f / tot;

  if (lane < 16) mid[wave][lane] = 0.f;
  __syncthreads();
#pragma unroll
  for (int c = 0; c < 4; ++c) {
#pragma unroll
    for (int e = 0; e < 4; ++e) {
      int j = c * 256 + lane * 4 + e;
      int tt = j - (s - 7);
      if (tt >= 0 && tt < 15) mid[wave][tt] = p[c][e];
    }
  }
  __syncthreads();

  float acc = sA * relv[lane] + sB * relv[16 * 64 + lane];
#pragma unroll
  for (int tt = 0; tt < 15; ++tt)
    acc += mid[wave][tt] * relv[(1 + tt) * 64 + lane];
  R[(size_t)row * 64 + lane] = acc * inv;

#pragma unroll
  for (int c = 0; c < 4; ++c) {
    short4_t o;
#pragma unroll
    for (int e = 0; e < 4; ++e) o[e] = (short)f2b(p[c][e] * inv);
    *reinterpret_cast<short4_t*>(P + (size_t)row * 1024 + c * 256 + lane * 4) = o;
  }
}

// ---------------------------------------------------------------------------
// Shared staging/compute macros (XOR swizzle source+read pair, rule 21).
// ---------------------------------------------------------------------------
#define STG(kt, buf)                                                        \
  {                                                                         \
    const int k0 = (kt) << 6;                                               \
    _Pragma("unroll")                                                       \
    for (int cc = 0; cc < 2; ++cc) {                                        \
      int c = threadIdx.x + (cc << 9);                                      \
      int r = c >> 3, cb = c & 7;                                           \
      int sc = k0 + ((cb ^ (r & 7)) << 3);                                  \
      gload16(A0 + (size_t)r * 1024 + sc, (char*)sA + (buf) * 16384 + c * 16); \
      gload16(B0 + (size_t)r * 1024 + sc, (char*)sB + (buf) * 16384 + c * 16); \
    }                                                                       \
  }

#define KSTEP_COMPUTE(bA, bB)                                               \
  _Pragma("unroll")                                                         \
  for (int kk = 0; kk < 2; ++kk) {                                          \
    const int cs = (kk << 2) + lk;                                          \
    short8 af[4], bf[2];                                                    \
    _Pragma("unroll")                                                       \
    for (int i = 0; i < 4; ++i) {                                           \
      int ra = (wm << 6) + (i << 4) + l15;                                  \
      af[i] = *reinterpret_cast<const short8*>(                             \
          (bA) + ra * 128 + ((cs ^ (ra & 7)) << 4));                        \
    }                                                                       \
    _Pragma("unroll")                                                       \
    for (int j = 0; j < 2; ++j) {                                           \
      int rb = (wn << 5) + (j << 4) + l15;                                  \
      bf[j] = *reinterpret_cast<const short8*>(                             \
          (bB) + rb * 128 + ((cs ^ (rb & 7)) << 4));                        \
    }                                                                       \
    __builtin_amdgcn_s_setprio(1);                                          \
    _Pragma("unroll")                                                       \
    for (int i = 0; i < 4; ++i)                                             \
      _Pragma("unroll")                                                     \
      for (int j = 0; j < 2; ++j)                                           \
        acc[i][j] = mfma16(af[i], bf[j], acc[i][j]);                        \
    __builtin_amdgcn_s_setprio(0);                                          \
  }

// ---------------------------------------------------------------------------
// 4-slot 128x128 GEMM core (VERIFIED rounds 7/10): depth-2 prefetch, counted
// vmcnt(8), one raw s_barrier per K-step. Slot reuse distance = 4 K-steps.
// ---------------------------------------------------------------------------
__device__ __forceinline__ void gemm128_loop4(
    const ushort_t* __restrict__ A0, const ushort_t* __restrict__ B0,
    ushort_t* sA, ushort_t* sB, floatx4 (&acc)[4][2])
{
  const int lane = threadIdx.x & 63, wave = threadIdx.x >> 6;
  const int wm = wave & 1, wn = wave >> 1;
  const int l15 = lane & 15, lk = lane >> 4;

  STG(0, 0);
  STG(1, 1);
  for (int kt = 0; kt < 16; ++kt) {
    if (kt < 14) {
      STG(kt + 2, (kt + 2) & 3);
      asm volatile("s_waitcnt vmcnt(8)" ::: "memory");
    } else if (kt == 14) {
      asm volatile("s_waitcnt vmcnt(4)" ::: "memory");
    } else {
      asm volatile("s_waitcnt vmcnt(0)" ::: "memory");
    }
    __builtin_amdgcn_s_barrier();
    const char* bA = (const char*)sA + (kt & 3) * 16384;
    const char* bB = (const char*)sB + (kt & 3) * 16384;
    KSTEP_COMPUTE(bA, bB);
  }
}

// bijective XCD swizzle for 256-block grids (256 % 8 == 0)
__device__ __forceinline__ int xcd_swz(int bid) {
  return ((bid & 7) << 5) | (bid >> 3);
}

// ---------------------------------------------------------------------------
// Device-wide barrier. Requires all 256 blocks co-resident (1 block/CU by
// 128KB LDS). Release: __syncthreads drains every thread's vmcnt (compiler
// emits vmcnt(0)+lgkmcnt(0) before s_barrier); thread0's __threadfence is an
// agent-scope release (L2 writeback -> cross-XCD visibility). Acquire:
// relaxed agent spin + __threadfence. Flags are monotonic within a launch;
// zeroed by hipMemsetAsync each launch (graph-replay deterministic).
// ---------------------------------------------------------------------------
__device__ __forceinline__ void gbar(unsigned* flag, unsigned target) {
  __syncthreads();
  if (threadIdx.x == 0) {
    __threadfence();
    __hip_atomic_fetch_add(flag, 1u, __ATOMIC_RELEASE, __HIP_MEMORY_SCOPE_AGENT);
    while (__hip_atomic_load(flag, __ATOMIC_RELAXED, __HIP_MEMORY_SCOPE_AGENT) < target)
      __builtin_amdgcn_s_sleep(8);
    __threadfence();
  }
  __syncthreads();
}

// ---------------------------------------------------------------------------
// D2: the three GEMMs as phases of one kernel, separated by gbar.
//   phase 1: Yt[h*256+b*64+d][s] = sum_k W_in[h*64+d][k]*x[b*1024+s][k]
//   phase 2: O[b][s][h*64+d]     = sum_j P[h][s][j]*Yt[h][b*64+d][j] + R
//   phase 3: out[m][n]           = sum_k O[m][k]*W_out[n][k]   (f32)
// Phase bodies are byte-level copies of the verified round-10 kernels.
// ---------------------------------------------------------------------------
__global__ __launch_bounds__(512) void k_gemm3(
    const ushort_t* __restrict__ Wib, const ushort_t* __restrict__ xb,
    ushort_t* __restrict__ Yt,
    const ushort_t* __restrict__ P, const float* __restrict__ R,
    ushort_t* __restrict__ O,
    const ushort_t* __restrict__ Wob, float* __restrict__ out,
    unsigned* __restrict__ flags)
{
  __shared__ ushort_t sA[4 * 128 * 64];
  __shared__ ushort_t sB[4 * 128 * 64];
  const int lg = xcd_swz(blockIdx.x);
  const int lane = threadIdx.x & 63, wave = threadIdx.x >> 6;
  const int wm = wave & 1, wn = wave >> 1;
  const int l15 = lane & 15, lk = lane >> 4;

  // ---------------- phase 1: gemm_xw ----------------
  {
    const int m0 = (lg & 7) << 7, n0 = (lg >> 3) << 7;
    const ushort_t* A0 = Wib + (size_t)m0 * 1024;
    const ushort_t* B0 = xb + (size_t)n0 * 1024;
    floatx4 acc[4][2] = {};
    gemm128_loop4(A0, B0, sA, sB, acc);
#pragma unroll
    for (int i = 0; i < 4; ++i)
#pragma unroll
      for (int j = 0; j < 2; ++j)
#pragma unroll
        for (int rr = 0; rr < 4; ++rr) {
          int wrow = m0 + (wm << 6) + (i << 4) + (lk << 2) + rr;  // h*64+d
          int col  = n0 + (wn << 5) + (j << 4) + l15;             // b*1024+s
          int h = wrow >> 6, d = wrow & 63;
          int b = col >> 10, s = col & 1023;
          Yt[(((size_t)((h << 2) + b) << 6) + d) * 1024 + s] = f2b(acc[i][j][rr]);
        }
  }
  gbar(flags + 0, 256u);

  // ---------------- phase 2: head_pv ----------------
  {
    const int h = lg >> 4, rem = lg & 15;
    const int m0 = (rem >> 1) << 7, n0 = (rem & 1) << 7;
    const ushort_t* A0 = P + ((size_t)h << 20) + (size_t)m0 * 1024;
    const ushort_t* B0 = Yt + ((size_t)h << 18) + (size_t)n0 * 1024;
    floatx4 acc[4][2] = {};
    gemm128_loop4(A0, B0, sA, sB, acc);
#pragma unroll
    for (int i = 0; i < 4; ++i)
#pragma unroll
      for (int j = 0; j < 2; ++j)
#pragma unroll
        for (int rr = 0; rr < 4; ++rr) {
          int sr = m0 + (wm << 6) + (i << 4) + (lk << 2) + rr;
          int c  = n0 + (wn << 5) + (j << 4) + l15;               // b*64+d
          int b = c >> 6, d = c & 63;
          float val = acc[i][j][rr] + R[(((size_t)h << 10) + sr) * 64 + d];
          O[((size_t)b << 20) + ((size_t)sr << 10) + (h << 6) + d] = f2b(val);
        }
  }
  gbar(flags + 1, 256u);

  // ---------------- phase 3: gemm_out ----------------
  {
    const int m0 = (lg >> 3) << 7, n0 = (lg & 7) << 7;
    const ushort_t* A0 = O + (size_t)m0 * 1024;
    const ushort_t* B0 = Wob + (size_t)n0 * 1024;
    floatx4 acc[4][2] = {};
    gemm128_loop4(A0, B0, sA, sB, acc);
#pragma unroll
    for (int i = 0; i < 4; ++i)
#pragma unroll
      for (int j = 0; j < 2; ++j)
#pragma unroll
        for (int rr = 0; rr < 4; ++rr) {
          int rowg = m0 + (wm << 6) + (i << 4) + (lk << 2) + rr;
          int colg = n0 + (wn << 5) + (j << 4) + l15;
          out[(size_t)rowg * 1024 + colg] = acc[i][j][rr];
        }
  }
}

// ---------------------------------------------------------------------------
extern "C" void kernel_launch(void* const* d_in, const int* in_sizes, int n_in,
                              void* d_out, int out_size, void* d_ws, size_t ws_size,
                              hipStream_t stream)
{
  const float* x     = (const float*)d_in[0];
  const float* W_in  = (const float*)d_in[1];
  const float* W_out = (const float*)d_in[2];
  const float* attn  = (const float*)d_in[3];
  const float* relv  = (const float*)d_in[4];
  float* out = (float*)d_out;

  char* ws = (char*)d_ws;
  ushort_t* xb  = (ushort_t*)(ws);                //  8 MB
  ushort_t* Wib = (ushort_t*)(ws + (8u << 20));   //  2 MB
  ushort_t* Wob = (ushort_t*)(ws + (10u << 20));  //  2 MB
  ushort_t* P   = (ushort_t*)(ws + (12u << 20));  // 32 MB
  float*    R   = (float*)   (ws + (44u << 20));  //  4 MB
  ushort_t* Yt  = (ushort_t*)(ws + (48u << 20));  //  8 MB  [h*256+b*64+d][s]
  ushort_t* O   = (ushort_t*)(ws + (56u << 20));  //  8 MB  [b][s][h*64+d]

  // barrier flags live in the last 64 B of d_out: only phase-3 stores touch
  // them (after they are dead); zeroed here each launch (replay-safe).
  unsigned* flags = (unsigned*)((char*)d_out + (size_t)out_size * 4 - 64);
  hipMemsetAsync(flags, 0, 64, stream);

  k_sm_f2b<<<7168, 256, 0, stream>>>(attn, relv, P, R, x, W_in, W_out, xb, Wib, Wob);
  k_gemm3<<<256, 512, 0, stream>>>(Wib, xb, Yt, P, R, O, Wob, out, flags);
}

// Round 14
// 64.356 us; speedup vs baseline: 1.7740x; 1.7740x over previous
//
#include <hip/hip_runtime.h>

typedef unsigned short ushort_t;
typedef __attribute__((ext_vector_type(8))) short short8;
typedef __attribute__((ext_vector_type(4))) float floatx4;
typedef __attribute__((ext_vector_type(8))) __bf16 bf16x8;

__device__ __forceinline__ ushort_t f2b(float f) {
  union { float f; unsigned int i; } t; t.f = f;
  unsigned int u = t.i;
  return (ushort_t)((u + 0x7fffu + ((u >> 16) & 1u)) >> 16);  // RNE
}
__device__ __forceinline__ float b2f(ushort_t u) {
  union { unsigned int i; float f; } t; t.i = ((unsigned int)u) << 16; return t.f;
}

__device__ __forceinline__ floatx4 mfma16(short8 a, short8 b, floatx4 c) {
  return __builtin_amdgcn_mfma_f32_16x16x32_bf16(
      __builtin_bit_cast(bf16x8, a), __builtin_bit_cast(bf16x8, b), c, 0, 0, 0);
}

__device__ __forceinline__ void gload16(const void* g, void* l) {
  __builtin_amdgcn_global_load_lds(
      (const __attribute__((address_space(1))) void*)g,
      (__attribute__((address_space(3))) void*)l, 16, 0, 0);
}

// ---------------------------------------------------------------------------
// D1: f2b of x/W_in/W_out (blocks 0..3071) + softmax+rel rows (blocks
// 3072..7167, 4 rows/block). Softmax uses the 8+8 contiguous per-lane layout
// (numerically verified in round 12's rider) -> 16B P stores. R in bf16.
// ---------------------------------------------------------------------------
__global__ __launch_bounds__(256) void k_sm_f2b(
    const float* __restrict__ S, const float* __restrict__ relv,
    ushort_t* __restrict__ P, ushort_t* __restrict__ Rb,
    const float* __restrict__ x, const float* __restrict__ Wi,
    const float* __restrict__ Wo, ushort_t* __restrict__ xb,
    ushort_t* __restrict__ Wib, ushort_t* __restrict__ Wob)
{
  __shared__ float mid[4][16];

  if (blockIdx.x < 3072) {
    const float* in; ushort_t* out; int i;
    if (blockIdx.x < 2048)      { in = x;  out = xb;  i = (blockIdx.x * 256 + threadIdx.x) * 8; }
    else if (blockIdx.x < 2560) { in = Wi; out = Wib; i = ((blockIdx.x - 2048) * 256 + threadIdx.x) * 8; }
    else                        { in = Wo; out = Wob; i = ((blockIdx.x - 2560) * 256 + threadIdx.x) * 8; }
    float4 a = *reinterpret_cast<const float4*>(in + i);
    float4 b = *reinterpret_cast<const float4*>(in + i + 4);
    short8 o;
    o[0] = (short)f2b(a.x); o[1] = (short)f2b(a.y);
    o[2] = (short)f2b(a.z); o[3] = (short)f2b(a.w);
    o[4] = (short)f2b(b.x); o[5] = (short)f2b(b.y);
    o[6] = (short)f2b(b.z); o[7] = (short)f2b(b.w);
    *reinterpret_cast<short8*>(out + i) = o;
    return;
  }

  const int wave = threadIdx.x >> 6, lane = threadIdx.x & 63;
  const int row = (blockIdx.x - 3072) * 4 + wave;   // h*1024 + s
  const int s = row & 1023;
  const float* src = S + ((size_t)row << 10) + (lane << 3);

  float4 a0 = *reinterpret_cast<const float4*>(src);
  float4 a1 = *reinterpret_cast<const float4*>(src + 4);
  float4 b0 = *reinterpret_cast<const float4*>(src + 512);
  float4 b1 = *reinterpret_cast<const float4*>(src + 516);
  float p0[8] = {a0.x, a0.y, a0.z, a0.w, a1.x, a1.y, a1.z, a1.w};
  float p1[8] = {b0.x, b0.y, b0.z, b0.w, b1.x, b1.y, b1.z, b1.w};

  float m = -3e38f;
#pragma unroll
  for (int e = 0; e < 8; ++e) m = fmaxf(m, fmaxf(p0[e], p1[e]));
#pragma unroll
  for (int d = 32; d; d >>= 1) m = fmaxf(m, __shfl_xor(m, d));

  float tot = 0.f, sA = 0.f, sB = 0.f;
#pragma unroll
  for (int e = 0; e < 8; ++e) {
    int j0 = (lane << 3) + e, j1 = 512 + (lane << 3) + e;
    float e0 = __expf(p0[e] - m), e1 = __expf(p1[e] - m);
    p0[e] = e0; p1[e] = e1;
    tot += e0 + e1;
    sA += ((j0 <= s - 8) ? e0 : 0.f) + ((j1 <= s - 8) ? e1 : 0.f);
    sB += ((j0 >= s + 8) ? e0 : 0.f) + ((j1 >= s + 8) ? e1 : 0.f);
  }
#pragma unroll
  for (int d = 32; d; d >>= 1) {
    tot += __shfl_xor(tot, d);
    sA  += __shfl_xor(sA, d);
    sB  += __shfl_xor(sB, d);
  }
  const float inv = 1.0f / tot;

  if (lane < 16) mid[wave][lane] = 0.f;
  __syncthreads();
#pragma unroll
  for (int e = 0; e < 8; ++e) {
    int j0 = (lane << 3) + e, j1 = 512 + (lane << 3) + e;
    int t0 = j0 - (s - 7), t1 = j1 - (s - 7);
    if (t0 >= 0 && t0 < 15) mid[wave][t0] = p0[e];
    if (t1 >= 0 && t1 < 15) mid[wave][t1] = p1[e];
  }
  __syncthreads();

  float acc = sA * relv[lane] + sB * relv[16 * 64 + lane];
#pragma unroll
  for (int tt = 0; tt < 15; ++tt)
    acc += mid[wave][tt] * relv[(1 + tt) * 64 + lane];
  Rb[((size_t)row << 6) + lane] = f2b(acc * inv);

  short8 o0, o1;
#pragma unroll
  for (int e = 0; e < 8; ++e) {
    o0[e] = (short)f2b(p0[e] * inv);
    o1[e] = (short)f2b(p1[e] * inv);
  }
  *reinterpret_cast<short8*>(P + ((size_t)row << 10) + (lane << 3)) = o0;
  *reinterpret_cast<short8*>(P + ((size_t)row << 10) + 512 + (lane << 3)) = o1;
}

// ---------------------------------------------------------------------------
// Shared staging/compute macros (XOR swizzle source+read pair, rule 21).
// ---------------------------------------------------------------------------
#define STG(kt, buf)                                                        \
  {                                                                         \
    const int k0 = (kt) << 6;                                               \
    _Pragma("unroll")                                                       \
    for (int cc = 0; cc < 2; ++cc) {                                        \
      int c = threadIdx.x + (cc << 9);                                      \
      int r = c >> 3, cb = c & 7;                                           \
      int sc = k0 + ((cb ^ (r & 7)) << 3);                                  \
      gload16(A0 + (size_t)r * 1024 + sc, (char*)sA + (buf) * 16384 + c * 16); \
      gload16(B0 + (size_t)r * 1024 + sc, (char*)sB + (buf) * 16384 + c * 16); \
    }                                                                       \
  }

#define KSTEP_COMPUTE(bA, bB)                                               \
  _Pragma("unroll")                                                         \
  for (int kk = 0; kk < 2; ++kk) {                                          \
    const int cs = (kk << 2) + lk;                                          \
    short8 af[4], bf[2];                                                    \
    _Pragma("unroll")                                                       \
    for (int i = 0; i < 4; ++i) {                                           \
      int ra = (wm << 6) + (i << 4) + l15;                                  \
      af[i] = *reinterpret_cast<const short8*>(                             \
          (bA) + ra * 128 + ((cs ^ (ra & 7)) << 4));                        \
    }                                                                       \
    _Pragma("unroll")                                                       \
    for (int j = 0; j < 2; ++j) {                                           \
      int rb = (wn << 5) + (j << 4) + l15;                                  \
      bf[j] = *reinterpret_cast<const short8*>(                             \
          (bB) + rb * 128 + ((cs ^ (rb & 7)) << 4));                        \
    }                                                                       \
    __builtin_amdgcn_s_setprio(1);                                          \
    _Pragma("unroll")                                                       \
    for (int i = 0; i < 4; ++i)                                             \
      _Pragma("unroll")                                                     \
      for (int j = 0; j < 2; ++j)                                           \
        acc[i][j] = mfma16(af[i], bf[j], acc[i][j]);                        \
    __builtin_amdgcn_s_setprio(0);                                          \
  }

// ---------------------------------------------------------------------------
// 4-slot 128x128 GEMM core (VERIFIED rounds 7/10): depth-2 prefetch, counted
// vmcnt(8), one raw s_barrier per K-step. Slot reuse distance = 4 K-steps.
// ---------------------------------------------------------------------------
__device__ __forceinline__ void gemm128_loop4(
    const ushort_t* __restrict__ A0, const ushort_t* __restrict__ B0,
    ushort_t* sA, ushort_t* sB, floatx4 (&acc)[4][2])
{
  const int lane = threadIdx.x & 63, wave = threadIdx.x >> 6;
  const int wm = wave & 1, wn = wave >> 1;
  const int l15 = lane & 15, lk = lane >> 4;

  STG(0, 0);
  STG(1, 1);
  for (int kt = 0; kt < 16; ++kt) {
    if (kt < 14) {
      STG(kt + 2, (kt + 2) & 3);
      asm volatile("s_waitcnt vmcnt(8)" ::: "memory");
    } else if (kt == 14) {
      asm volatile("s_waitcnt vmcnt(4)" ::: "memory");
    } else {
      asm volatile("s_waitcnt vmcnt(0)" ::: "memory");
    }
    __builtin_amdgcn_s_barrier();
    const char* bA = (const char*)sA + (kt & 3) * 16384;
    const char* bB = (const char*)sB + (kt & 3) * 16384;
    KSTEP_COMPUTE(bA, bB);
  }
}

// bijective XCD swizzle for 256-block grids (256 % 8 == 0)
__device__ __forceinline__ int xcd_swz(int bid) {
  return ((bid & 7) << 5) | (bid >> 3);
}

// ---------------------------------------------------------------------------
// D2: GEMM 1: Yt[h*256+b*64+d][s] = sum_k W_in[h*64+d][k] * x[b*1024+s][k]
// ---------------------------------------------------------------------------
__global__ __launch_bounds__(512) void k_gemm_xw(
    const ushort_t* __restrict__ W, const ushort_t* __restrict__ X,
    ushort_t* __restrict__ Yt)
{
  __shared__ ushort_t sA[4 * 128 * 64];
  __shared__ ushort_t sB[4 * 128 * 64];
  const int lg = xcd_swz(blockIdx.x);
  const int m0 = (lg & 7) << 7, n0 = (lg >> 3) << 7;
  const ushort_t* A0 = W + (size_t)m0 * 1024;
  const ushort_t* B0 = X + (size_t)n0 * 1024;
  floatx4 acc[4][2] = {};
  gemm128_loop4(A0, B0, sA, sB, acc);

  const int lane = threadIdx.x & 63, wave = threadIdx.x >> 6;
  const int wm = wave & 1, wn = wave >> 1;
  const int l15 = lane & 15, lk = lane >> 4;
#pragma unroll
  for (int i = 0; i < 4; ++i)
#pragma unroll
    for (int j = 0; j < 2; ++j)
#pragma unroll
      for (int rr = 0; rr < 4; ++rr) {
        int wrow = m0 + (wm << 6) + (i << 4) + (lk << 2) + rr;  // h*64+d
        int col  = n0 + (wn << 5) + (j << 4) + l15;             // b*1024+s
        int h = wrow >> 6, d = wrow & 63;
        int b = col >> 10, s = col & 1023;
        Yt[(((size_t)((h << 2) + b) << 6) + d) * 1024 + s] = f2b(acc[i][j][rr]);
      }
}

// ---------------------------------------------------------------------------
// D3: PV GEMM: O[b][s][h*64+d] = sum_j P[h][s][j]*Yt[h][b*64+d][j] + R[h][s][d]
// R read as bf16.
// ---------------------------------------------------------------------------
__global__ __launch_bounds__(512) void k_head_pv(
    const ushort_t* __restrict__ P, const ushort_t* __restrict__ Yt,
    const ushort_t* __restrict__ Rb, ushort_t* __restrict__ O)
{
  __shared__ ushort_t sA[4 * 128 * 64];
  __shared__ ushort_t sB[4 * 128 * 64];
  const int lg = xcd_swz(blockIdx.x);
  const int h = lg >> 4, rem = lg & 15;
  const int m0 = (rem >> 1) << 7, n0 = (rem & 1) << 7;
  const ushort_t* A0 = P + ((size_t)h << 20) + (size_t)m0 * 1024;
  const ushort_t* B0 = Yt + ((size_t)h << 18) + (size_t)n0 * 1024;
  floatx4 acc[4][2] = {};
  gemm128_loop4(A0, B0, sA, sB, acc);

  const int lane = threadIdx.x & 63, wave = threadIdx.x >> 6;
  const int wm = wave & 1, wn = wave >> 1;
  const int l15 = lane & 15, lk = lane >> 4;
#pragma unroll
  for (int i = 0; i < 4; ++i)
#pragma unroll
    for (int j = 0; j < 2; ++j)
#pragma unroll
      for (int rr = 0; rr < 4; ++rr) {
        int sr = m0 + (wm << 6) + (i << 4) + (lk << 2) + rr;
        int c  = n0 + (wn << 5) + (j << 4) + l15;               // b*64+d
        int b = c >> 6, d = c & 63;
        float val = acc[i][j][rr] + b2f(Rb[(((size_t)h << 10) + sr) * 64 + d]);
        O[((size_t)b << 20) + ((size_t)sr << 10) + (h << 6) + d] = f2b(val);
      }
}

// ---------------------------------------------------------------------------
// D4: out[m][n] = sum_k O[m][k] * W_out[n][k]  (f32 out).
// ---------------------------------------------------------------------------
__global__ __launch_bounds__(512) void k_gemm_out(
    const ushort_t* __restrict__ A, const ushort_t* __restrict__ B,
    float* __restrict__ C)
{
  __shared__ ushort_t sA[4 * 128 * 64];
  __shared__ ushort_t sB[4 * 128 * 64];
  const int lg = xcd_swz(blockIdx.x);
  const int m0 = (lg >> 3) << 7, n0 = (lg & 7) << 7;
  const ushort_t* A0 = A + (size_t)m0 * 1024;
  const ushort_t* B0 = B + (size_t)n0 * 1024;
  floatx4 acc[4][2] = {};
  gemm128_loop4(A0, B0, sA, sB, acc);

  const int lane = threadIdx.x & 63, wave = threadIdx.x >> 6;
  const int wm = wave & 1, wn = wave >> 1;
  const int l15 = lane & 15, lk = lane >> 4;
#pragma unroll
  for (int i = 0; i < 4; ++i)
#pragma unroll
    for (int j = 0; j < 2; ++j)
#pragma unroll
      for (int rr = 0; rr < 4; ++rr) {
        int rowg = m0 + (wm << 6) + (i << 4) + (lk << 2) + rr;
        int colg = n0 + (wn << 5) + (j << 4) + l15;
        C[(size_t)rowg * 1024 + colg] = acc[i][j][rr];
      }
}

// ---------------------------------------------------------------------------
extern "C" void kernel_launch(void* const* d_in, const int* in_sizes, int n_in,
                              void* d_out, int out_size, void* d_ws, size_t ws_size,
                              hipStream_t stream)
{
  const float* x     = (const float*)d_in[0];
  const float* W_in  = (const float*)d_in[1];
  const float* W_out = (const float*)d_in[2];
  const float* attn  = (const float*)d_in[3];
  const float* relv  = (const float*)d_in[4];
  float* out = (float*)d_out;

  char* ws = (char*)d_ws;
  ushort_t* xb  = (ushort_t*)(ws);                //  8 MB
  ushort_t* Wib = (ushort_t*)(ws + (8u << 20));   //  2 MB
  ushort_t* Wob = (ushort_t*)(ws + (10u << 20));  //  2 MB
  ushort_t* P   = (ushort_t*)(ws + (12u << 20));  // 32 MB
  ushort_t* Rb  = (ushort_t*)(ws + (44u << 20));  //  2 MB (bf16)
  ushort_t* Yt  = (ushort_t*)(ws + (48u << 20));  //  8 MB  [h*256+b*64+d][s]
  ushort_t* O   = (ushort_t*)(ws + (56u << 20));  //  8 MB  [b][s][h*64+d]

  k_sm_f2b<<<7168, 256, 0, stream>>>(attn, relv, P, Rb, x, W_in, W_out, xb, Wib, Wob);
  k_gemm_xw<<<256, 512, 0, stream>>>(Wib, xb, Yt);
  k_head_pv<<<256, 512, 0, stream>>>(P, Yt, Rb, O);
  k_gemm_out<<<256, 512, 0, stream>>>(O, Wob, out);
}